// Round 1
// baseline (974.072 us; speedup 1.0000x reference)
//
#include <hip/hip_runtime.h>
#include <math.h>

#define BH 64
#define N 1024
#define D 64
#define TM 32           // q rows per block
#define TK 64           // k rows per chunk
#define NCHUNK (N / TK) // 16
#define QSTRIDE 68      // pad: 68%32==4 -> distinct banks across rows, 16B-aligned rows
#define KSTRIDE 68
#define ASTRIDE 72      // 72%32==8 -> 2-way aliasing only (free)

__global__ __launch_bounds__(256) void attn_fused_kernel(
    const float* __restrict__ q, const float* __restrict__ k,
    const float* __restrict__ v, const float* __restrict__ qs,
    const float* __restrict__ ks,
    float* __restrict__ out_o, float* __restrict__ out_a,
    float* __restrict__ out_s)
{
    __shared__ float qf[TM][QSTRIDE];
    __shared__ float stage[TK][KSTRIDE];   // kf chunk in pass 1, v chunk in pass 2
    __shared__ float attn_st[TM][ASTRIDE];
    __shared__ float rowsum[TM];

    const int t  = threadIdx.x;
    const int b  = blockIdx.y;
    const int q0 = blockIdx.x * TM;

    const int r = t >> 3;  // 0..31 : q row within tile
    const int p = t & 7;   // 0..7  : column phase

    // ---- load fused Q tile (32x64) ----
    {
        const float4* qg  = (const float4*)(q  + (size_t)b * N * D + (size_t)q0 * D);
        const float4* qsg = (const float4*)(qs + (size_t)b * N * D + (size_t)q0 * D);
        for (int i = t; i < TM * D / 4; i += 256) {
            int row = i >> 4, dv = i & 15;
            float4 a = qg[i], c = qsg[i];
            float4 s4;
            s4.x = a.x + c.x; s4.y = a.y + c.y; s4.z = a.z + c.z; s4.w = a.w + c.w;
            ((float4*)&qf[row][0])[dv] = s4;
        }
    }

    const size_t score_base = (size_t)b * N * N + (size_t)q0 * N;

    // ---- pass 1: scores + exp row-sums ----
    float rs = 0.0f;
    for (int kc = 0; kc < NCHUNK; ++kc) {
        __syncthreads();
        const float4* kg  = (const float4*)(k  + (size_t)b * N * D + (size_t)kc * TK * D);
        const float4* ksg = (const float4*)(ks + (size_t)b * N * D + (size_t)kc * TK * D);
        for (int i = t; i < TK * D / 4; i += 256) {
            int row = i >> 4, dv = i & 15;
            float4 a = kg[i], c = ksg[i];
            float4 s4;
            s4.x = a.x + c.x; s4.y = a.y + c.y; s4.z = a.z + c.z; s4.w = a.w + c.w;
            ((float4*)&stage[row][0])[dv] = s4;
        }
        __syncthreads();

        const float4* qrow = (const float4*)&qf[r][0];
        for (int j = 0; j < 8; ++j) {
            int cl = p + 8 * j;
            const float4* krow = (const float4*)&stage[cl][0];
            float s = 0.0f;
#pragma unroll
            for (int dv = 0; dv < 16; ++dv) {
                float4 a = qrow[dv], bb = krow[dv];
                s += a.x * bb.x + a.y * bb.y + a.z * bb.z + a.w * bb.w;
            }
            s *= 0.125f; // 1/TEMPERATURE
            out_s[score_base + (size_t)r * N + kc * TK + cl] = s;
            rs += __expf(s);
        }
    }

    // reduce row sum across the 8 lanes of this row (consecutive lanes, same wave)
    for (int off = 1; off < 8; off <<= 1) rs += __shfl_xor(rs, off);
    if (p == 0) rowsum[r] = rs;
    __syncthreads();
    const float inv = 1.0f / rowsum[r];

    // ---- pass 2: attn + output ----
    float acc[8];
#pragma unroll
    for (int i = 0; i < 8; ++i) acc[i] = 0.0f;
    const int d0 = p * 8;

    for (int kc = 0; kc < NCHUNK; ++kc) {
        __syncthreads(); // protect stage/attn_st reuse
        const float4* vg = (const float4*)(v + (size_t)b * N * D + (size_t)kc * TK * D);
        for (int i = t; i < TK * D / 4; i += 256) {
            int row = i >> 4, dv = i & 15;
            ((float4*)&stage[row][0])[dv] = vg[i];
        }
        for (int j = 0; j < 8; ++j) {
            int cl = p + 8 * j;
            float s = out_s[score_base + (size_t)r * N + kc * TK + cl];
            float a = __expf(s) * inv;
            out_a[score_base + (size_t)r * N + kc * TK + cl] = a;
            attn_st[r][cl] = a;
        }
        __syncthreads();
#pragma unroll 4
        for (int c = 0; c < TK; ++c) {
            float a = attn_st[r][c];
            const float4* vrow = (const float4*)&stage[c][d0];
            float4 v0 = vrow[0], v1 = vrow[1];
            acc[0] += a * v0.x; acc[1] += a * v0.y;
            acc[2] += a * v0.z; acc[3] += a * v0.w;
            acc[4] += a * v1.x; acc[5] += a * v1.y;
            acc[6] += a * v1.z; acc[7] += a * v1.w;
        }
    }

    float* op = out_o + (size_t)b * N * D + (size_t)(q0 + r) * D + d0;
    float4 o0 = make_float4(acc[0], acc[1], acc[2], acc[3]);
    float4 o1 = make_float4(acc[4], acc[5], acc[6], acc[7]);
    ((float4*)op)[0] = o0;
    ((float4*)op)[1] = o1;
}

extern "C" void kernel_launch(void* const* d_in, const int* in_sizes, int n_in,
                              void* d_out, int out_size, void* d_ws, size_t ws_size,
                              hipStream_t stream) {
    const float* q  = (const float*)d_in[0];
    const float* k  = (const float*)d_in[1];
    const float* v  = (const float*)d_in[2];
    const float* qs = (const float*)d_in[3];
    const float* ks = (const float*)d_in[4];

    float* out_o = (float*)d_out;                       // [64,1024,64]
    float* out_a = out_o + (size_t)BH * N * D;          // [64,1024,1024]
    float* out_s = out_a + (size_t)BH * N * N;          // [64,1024,1024]

    dim3 grid(N / TM, BH);
    dim3 block(256);
    attn_fused_kernel<<<grid, block, 0, stream>>>(q, k, v, qs, ks, out_o, out_a, out_s);
}